// Round 5
// baseline (651.105 us; speedup 1.0000x reference)
//
#include <hip/hip_runtime.h>
#include <hip/hip_bf16.h>
#include <stdint.h>

#define B_TOK 65536
#define DM 1024
#define NC 1024
#define NT 16
#define GAPTHR 0.25f

typedef __attribute__((ext_vector_type(4))) float f32x4;
typedef __attribute__((ext_vector_type(4))) unsigned int u32x4;
typedef __attribute__((ext_vector_type(4))) unsigned short u16x4;
typedef __attribute__((ext_vector_type(8))) short short8;

#define AS1(p) ((__attribute__((address_space(1))) void*)(p))
#define AS3(p) ((__attribute__((address_space(3))) void*)(p))

static __device__ inline unsigned short f2bf(float f) {
  __hip_bfloat16 h = __float2bfloat16(f);
  unsigned short u;
  __builtin_memcpy(&u, &h, 2);
  return u;
}

// ---- prep: ternary masks (bit t = pos, bit 16+t = neg) + ternary bf16 matrix S[16][1024] ----
__global__ void k_prep(const float* __restrict__ sigs, unsigned int* __restrict__ mask,
                       unsigned short* __restrict__ Sb) {
  int d = threadIdx.x;
  unsigned int m = 0;
#pragma unroll
  for (int t = 0; t < NT; ++t) {
    float s = sigs[t * DM + d];
    float q = (s > 0.3f) ? 1.0f : ((s < -0.3f) ? -1.0f : 0.0f);
    if (s > 0.3f) m |= 1u << t;
    else if (s < -0.3f) m |= 1u << (16 + t);
    Sb[t * DM + d] = f2bf(q);   // {-1,0,1} exact in bf16
  }
  mask[d] = m;
}

// ---- provisional scores via bf16 MFMA + top-2 gap + x->bf16 ----
__global__ __launch_bounds__(256) void k_scores(const float* __restrict__ x,
    const unsigned short* __restrict__ Sb, unsigned short* __restrict__ xb,
    int* __restrict__ tidx, float* __restrict__ oidx,
    int* __restrict__ fixlist, int* __restrict__ nfix)
{
  int tid = threadIdx.x;
  int w = tid >> 6, l = tid & 63;
  int lr = l & 15, lg = l >> 4;
  int tok0 = blockIdx.x * 64 + w * 16;

  const float* xr = x + (size_t)(tok0 + lr) * DM + lg * 8;
  unsigned short* xbr = xb + (size_t)(tok0 + lr) * DM + lg * 8;
  const unsigned short* sr = Sb + (size_t)lr * DM + lg * 8;

  f32x4 acc = (f32x4){0.f, 0.f, 0.f, 0.f};
  for (int kc = 0; kc < 32; ++kc) {
    f32x4 v0 = *(const f32x4*)(xr + kc * 32);
    f32x4 v1 = *(const f32x4*)(xr + kc * 32 + 4);
    short8 a;
#pragma unroll
    for (int j = 0; j < 4; ++j) {
      a[j]     = (short)f2bf(v0[j]);
      a[4 + j] = (short)f2bf(v1[j]);
    }
    *(short8*)(xbr + kc * 32) = a;
    short8 b = *(const short8*)(sr + kc * 32);
    acc = __builtin_amdgcn_mfma_f32_16x16x32_bf16(a, b, acc, 0, 0, 0);
  }

  // D: lane(lr,lg) reg i = score[token=lg*4+i][tile=lr]. Top-2 reduce over tile axis (lr).
  float m1[4], m2v[4]; int i1[4];
#pragma unroll
  for (int i = 0; i < 4; ++i) { m1[i] = acc[i]; i1[i] = lr; m2v[i] = -1e30f; }
#pragma unroll
  for (int off = 1; off < 16; off <<= 1) {
#pragma unroll
    for (int i = 0; i < 4; ++i) {
      float bm  = __shfl_xor(m1[i], off);
      int   bi  = __shfl_xor(i1[i], off);
      float bm2 = __shfl_xor(m2v[i], off);
      bool bwin = (bm > m1[i]) || (bm == m1[i] && bi < i1[i]);
      float loser = bwin ? m1[i] : bm;
      m2v[i] = fmaxf(fmaxf(m2v[i], bm2), loser);
      if (bwin) { m1[i] = bm; i1[i] = bi; }
    }
  }
  if (lr == 0) {
#pragma unroll
    for (int i = 0; i < 4; ++i) {
      int tok = tok0 + lg * 4 + i;
      tidx[tok] = i1[i];
      oidx[tok] = (float)i1[i];
      if (m1[i] - m2v[i] < GAPTHR) {
        int p = atomicAdd(nfix, 1);
        fixlist[p] = tok;
      }
    }
  }
}

// ---- exact f64 rescore for close-call tokens (one wave per token) ----
__global__ __launch_bounds__(256) void k_fix(const float* __restrict__ x,
    const unsigned int* __restrict__ mask, const int* __restrict__ fixlist,
    const int* __restrict__ nfix, int* __restrict__ tidx, float* __restrict__ oidx)
{
  int n = *nfix;
  int l = threadIdx.x & 63;
  int gw = (blockIdx.x * 256 + threadIdx.x) >> 6;
  int nw = (gridDim.x * 256) >> 6;
  int t = l & 15, seg = l >> 4;

  for (int i = gw; i < n; i += nw) {
    int tok = fixlist[i];
    const float* xr = x + (size_t)tok * DM + seg * 256;
    const unsigned int* mr = mask + seg * 256;
    double acc0 = 0.0, acc1 = 0.0;
    for (int j = 0; j < 256; j += 4) {
      f32x4 xv = *(const f32x4*)(xr + j);
      u32x4 mv = *(const u32x4*)(mr + j);
#pragma unroll
      for (int u = 0; u < 4; ++u) {
        double c = ((mv[u] >> t) & 1u) ? (double)xv[u]
                 : (((mv[u] >> (16 + t)) & 1u) ? -(double)xv[u] : 0.0);
        if (u & 1) acc1 += c; else acc0 += c;
      }
    }
    double s = acc0 + acc1;
    s += __shfl_xor(s, 16);
    s += __shfl_xor(s, 32);
    double bv = s; int bi = t;
#pragma unroll
    for (int off = 1; off < 16; off <<= 1) {
      double ov = __shfl_xor(bv, off);
      int   oi = __shfl_xor(bi, off);
      if (ov > bv || (ov == bv && oi < bi)) { bv = ov; bi = oi; }
    }
    if (l == 0) { tidx[tok] = bi; oidx[tok] = (float)bi; }
  }
}

// ---- histogram of final routing ----
__global__ __launch_bounds__(256) void k_count(const int* __restrict__ tidx, int* __restrict__ counts) {
  __shared__ int h[16];
  if (threadIdx.x < 16) h[threadIdx.x] = 0;
  __syncthreads();
  int i = blockIdx.x * 256 + threadIdx.x;
  atomicAdd(&h[tidx[i]], 1);
  __syncthreads();
  if (threadIdx.x < 16 && h[threadIdx.x]) atomicAdd(&counts[threadIdx.x], h[threadIdx.x]);
}

// ---- W f32 -> bf16 ----
__global__ __launch_bounds__(256) void k_wconv(const float* __restrict__ W, unsigned short* __restrict__ Wb) {
  const f32x4* W4 = (const f32x4*)W;
  u16x4* O = (u16x4*)Wb;
  int n4 = NT * NC * DM / 4;
  for (int i = blockIdx.x * blockDim.x + threadIdx.x; i < n4; i += gridDim.x * blockDim.x) {
    f32x4 v = W4[i];
    u16x4 o;
#pragma unroll
    for (int j = 0; j < 4; ++j) o[j] = f2bf(v[j]);
    O[i] = o;
  }
}

// ---- padded exclusive scan of counts (pad to 128) ----
__global__ void k_scan(const int* __restrict__ counts, int* __restrict__ offs) {
  if (threadIdx.x == 0) {
    int s = 0;
    for (int t = 0; t < NT; ++t) {
      offs[t] = s;
      s += (counts[t] + 127) & ~127;
    }
    offs[NT] = s;
  }
}

// ---- scatter tokens into per-tile segments ----
__global__ __launch_bounds__(256) void k_place(const int* __restrict__ tidx, const int* __restrict__ offs,
                                               int* __restrict__ cursor, int* __restrict__ perm) {
  int tok = blockIdx.x * 256 + threadIdx.x;
  if (tok >= B_TOK) return;
  int t = tidx[tok];
  int pos = atomicAdd(&cursor[t], 1);
  perm[offs[t] + pos] = tok;
}

// ---- grouped GEMM: 128x128, BK=64, XOR-swizzled LDS (T2) + 2-phase dbuf pipeline (T3/T4) ----
// Double-buffered: issue next K-tile's global_load_lds BEFORE computing current tile; raw
// s_barrier + counted s_waitcnt vmcnt(8) keeps 8 prefetch loads in flight across barriers
// (never drain to 0 mid-loop). Loads into buf X only issue after the barrier certifying all
// waves finished reading X (2nd barrier of the prior iteration).
__global__ __launch_bounds__(256) void k_gemm(const unsigned short* __restrict__ xb,
    const unsigned short* __restrict__ Wb, const float* __restrict__ bias,
    const int* __restrict__ perm, const int* __restrict__ offs, float* __restrict__ out)
{
  __shared__ unsigned short As[2][128 * 64];
  __shared__ unsigned short Bs[2][128 * 64];
  int bid0 = blockIdx.x;
  int bid = (bid0 & 7) * 528 + (bid0 >> 3);   // bijective XCD swizzle (4224 = 8*528)
  int mb = bid >> 3, nb = bid & 7;
  int total = offs[NT];
  int m0 = mb << 7;
  if (m0 >= total) return;
  int t = 0;
#pragma unroll
  for (int tt = 0; tt < NT; ++tt) if (m0 >= offs[tt + 1]) t = tt + 1;
  int c0 = nb << 7;
  int tid = threadIdx.x;

  int rowg = tid >> 3;                                   // 0..31
  int ks8 = (((tid & 7) ^ (rowg & 7)) << 3);             // swizzled global k-offset (elements)
  const unsigned short* gA[4];
  const unsigned short* gB[4];
  const unsigned short* gWt = Wb + (size_t)t * NC * DM;
#pragma unroll
  for (int r = 0; r < 4; ++r) {
    int row = r * 32 + rowg;                             // row&7 == rowg&7
    int tk = perm[m0 + row]; if (tk < 0) tk = 0;
    gA[r] = xb + (size_t)tk * DM + ks8;
    gB[r] = gWt + (size_t)(c0 + row) * DM + ks8;
  }

  f32x4 acc[4][4];
#pragma unroll
  for (int m = 0; m < 4; ++m)
#pragma unroll
    for (int n = 0; n < 4; ++n) acc[m][n] = (f32x4){0.f, 0.f, 0.f, 0.f};

  int w = tid >> 6, l = tid & 63;
  int wr = w >> 1, wc = w & 1;
  int lr = l & 15, lk = l >> 4;
  int sx = lr & 7;                                       // row&7 on the read side

#define STAGE(BUF, KT) \
  { int kk_ = (KT) << 6; \
    _Pragma("unroll") \
    for (int r_ = 0; r_ < 4; ++r_) { \
      __builtin_amdgcn_global_load_lds(AS1(gA[r_] + kk_), AS3(&As[BUF][(r_ * 256 + tid) * 8]), 16, 0, 0); \
      __builtin_amdgcn_global_load_lds(AS1(gB[r_] + kk_), AS3(&Bs[BUF][(r_ * 256 + tid) * 8]), 16, 0, 0); \
    } }

#define COMPUTE(BUF) \
  { _Pragma("unroll") \
    for (int ks_ = 0; ks_ < 2; ++ks_) { \
      short8 a_[4], b_[4]; \
      _Pragma("unroll") \
      for (int m_ = 0; m_ < 4; ++m_) \
        a_[m_] = *(const short8*)&As[BUF][(wr * 64 + m_ * 16 + lr) * 64 + (((ks_ * 4 + lk) ^ sx) << 3)]; \
      _Pragma("unroll") \
      for (int n_ = 0; n_ < 4; ++n_) \
        b_[n_] = *(const short8*)&Bs[BUF][(wc * 64 + n_ * 16 + lr) * 64 + (((ks_ * 4 + lk) ^ sx) << 3)]; \
      _Pragma("unroll") \
      for (int m_ = 0; m_ < 4; ++m_) \
        _Pragma("unroll") \
        for (int n_ = 0; n_ < 4; ++n_) \
          acc[m_][n_] = __builtin_amdgcn_mfma_f32_16x16x32_bf16(a_[m_], b_[n_], acc[m_][n_], 0, 0, 0); \
    } }

#define PIPE_STEP(CUR, NXT, KT) \
  { if ((KT) < 15) { \
      STAGE(NXT, (KT) + 1); \
      asm volatile("s_waitcnt vmcnt(8)" ::: "memory"); \
    } else { \
      asm volatile("s_waitcnt vmcnt(0)" ::: "memory"); \
    } \
    __builtin_amdgcn_s_barrier(); \
    COMPUTE(CUR); \
    __builtin_amdgcn_s_barrier(); \
    __builtin_amdgcn_sched_barrier(0); }

  STAGE(0, 0);                       // prologue: tile 0 -> buf 0
  for (int kt = 0; kt < 16; kt += 2) {
    PIPE_STEP(0, 1, kt);
    PIPE_STEP(1, 0, kt + 1);
  }
#undef PIPE_STEP
#undef COMPUTE
#undef STAGE

  float bv[4];
#pragma unroll
  for (int n = 0; n < 4; ++n) bv[n] = bias[t * NC + c0 + wc * 64 + n * 16 + lr];
#pragma unroll
  for (int m = 0; m < 4; ++m) {
#pragma unroll
    for (int j = 0; j < 4; ++j) {
      int prow = m0 + wr * 64 + m * 16 + lk * 4 + j;
      int tok = perm[prow];
      if (tok >= 0) {
#pragma unroll
        for (int n = 0; n < 4; ++n)
          out[(size_t)tok * NC + c0 + wc * 64 + n * 16 + lr] = acc[m][n][j] + bv[n];
      }
    }
  }
}

extern "C" void kernel_launch(void* const* d_in, const int* in_sizes, int n_in,
                              void* d_out, int out_size, void* d_ws, size_t ws_size,
                              hipStream_t stream) {
  const float* x    = (const float*)d_in[0];
  const float* sigs = (const float*)d_in[1];
  const float* W    = (const float*)d_in[2];
  const float* bias = (const float*)d_in[3];
  float* out = (float*)d_out;
  float* oidx = out + (size_t)B_TOK * NC;

  char* ws = (char*)d_ws;
  unsigned short* xb   = (unsigned short*)ws;                    // 134217728 B
  unsigned short* Wb   = (unsigned short*)(ws + 134217728);      // 33554432 B
  int* perm            = (int*)(ws + 167772160);                 // 270336 B (67584 rows)
  int* tidx            = (int*)(ws + 168042496);                 // 262144 B
  unsigned int* mask   = (unsigned int*)(ws + 168304640);        // 4096 B
  unsigned short* Sb   = (unsigned short*)(ws + 168308736);      // 32768 B
  int* fixlist         = (int*)(ws + 168341504);                 // 262144 B
  int* ctrl            = (int*)(ws + 168603648);                 // counts16 cursor16 offs17 nfix1
  int* counts = ctrl;
  int* cursor = ctrl + 16;
  int* offs   = ctrl + 32;
  int* nfix   = ctrl + 49;

  hipMemsetAsync(perm, 0xFF, 270336, stream);   // perm = -1 (pad marker)
  hipMemsetAsync(ctrl, 0, 256, stream);

  k_prep<<<1, 1024, 0, stream>>>(sigs, mask, Sb);
  k_scores<<<1024, 256, 0, stream>>>(x, Sb, xb, tidx, oidx, fixlist, nfix);
  k_fix<<<512, 256, 0, stream>>>(x, mask, fixlist, nfix, tidx, oidx);
  k_count<<<256, 256, 0, stream>>>(tidx, counts);
  k_scan<<<1, 64, 0, stream>>>(counts, offs);
  k_place<<<256, 256, 0, stream>>>(tidx, offs, cursor, perm);
  k_wconv<<<2048, 256, 0, stream>>>(W, Wb);
  k_gemm<<<dim3(528 * 8), 256, 0, stream>>>(xb, Wb, bias, perm, offs, out);
}

// Round 6
// 572.317 us; speedup vs baseline: 1.1377x; 1.1377x over previous
//
#include <hip/hip_runtime.h>
#include <hip/hip_bf16.h>
#include <stdint.h>

#define B_TOK 65536
#define DM 1024
#define NC 1024
#define NT 16
#define GAPTHR 0.25f

typedef __attribute__((ext_vector_type(4))) float f32x4;
typedef __attribute__((ext_vector_type(4))) unsigned int u32x4;
typedef __attribute__((ext_vector_type(4))) unsigned short u16x4;
typedef __attribute__((ext_vector_type(8))) short short8;

#define AS1(p) ((__attribute__((address_space(1))) void*)(p))
#define AS3(p) ((__attribute__((address_space(3))) void*)(p))

static __device__ inline unsigned short f2bf(float f) {
  __hip_bfloat16 h = __float2bfloat16(f);
  unsigned short u;
  __builtin_memcpy(&u, &h, 2);
  return u;
}

// ---- prep: ternary masks (bit t = pos, bit 16+t = neg) + ternary bf16 matrix S[16][1024] ----
__global__ void k_prep(const float* __restrict__ sigs, unsigned int* __restrict__ mask,
                       unsigned short* __restrict__ Sb) {
  int d = threadIdx.x;
  unsigned int m = 0;
#pragma unroll
  for (int t = 0; t < NT; ++t) {
    float s = sigs[t * DM + d];
    float q = (s > 0.3f) ? 1.0f : ((s < -0.3f) ? -1.0f : 0.0f);
    if (s > 0.3f) m |= 1u << t;
    else if (s < -0.3f) m |= 1u << (16 + t);
    Sb[t * DM + d] = f2bf(q);   // {-1,0,1} exact in bf16
  }
  mask[d] = m;
}

// ---- provisional scores via bf16 MFMA + top-2 gap + x->bf16 ----
__global__ __launch_bounds__(256) void k_scores(const float* __restrict__ x,
    const unsigned short* __restrict__ Sb, unsigned short* __restrict__ xb,
    int* __restrict__ tidx, float* __restrict__ oidx,
    int* __restrict__ fixlist, int* __restrict__ nfix)
{
  int tid = threadIdx.x;
  int w = tid >> 6, l = tid & 63;
  int lr = l & 15, lg = l >> 4;
  int tok0 = blockIdx.x * 64 + w * 16;

  const float* xr = x + (size_t)(tok0 + lr) * DM + lg * 8;
  unsigned short* xbr = xb + (size_t)(tok0 + lr) * DM + lg * 8;
  const unsigned short* sr = Sb + (size_t)lr * DM + lg * 8;

  f32x4 acc = (f32x4){0.f, 0.f, 0.f, 0.f};
  for (int kc = 0; kc < 32; ++kc) {
    f32x4 v0 = *(const f32x4*)(xr + kc * 32);
    f32x4 v1 = *(const f32x4*)(xr + kc * 32 + 4);
    short8 a;
#pragma unroll
    for (int j = 0; j < 4; ++j) {
      a[j]     = (short)f2bf(v0[j]);
      a[4 + j] = (short)f2bf(v1[j]);
    }
    *(short8*)(xbr + kc * 32) = a;
    short8 b = *(const short8*)(sr + kc * 32);
    acc = __builtin_amdgcn_mfma_f32_16x16x32_bf16(a, b, acc, 0, 0, 0);
  }

  float m1[4], m2v[4]; int i1[4];
#pragma unroll
  for (int i = 0; i < 4; ++i) { m1[i] = acc[i]; i1[i] = lr; m2v[i] = -1e30f; }
#pragma unroll
  for (int off = 1; off < 16; off <<= 1) {
#pragma unroll
    for (int i = 0; i < 4; ++i) {
      float bm  = __shfl_xor(m1[i], off);
      int   bi  = __shfl_xor(i1[i], off);
      float bm2 = __shfl_xor(m2v[i], off);
      bool bwin = (bm > m1[i]) || (bm == m1[i] && bi < i1[i]);
      float loser = bwin ? m1[i] : bm;
      m2v[i] = fmaxf(fmaxf(m2v[i], bm2), loser);
      if (bwin) { m1[i] = bm; i1[i] = bi; }
    }
  }
  if (lr == 0) {
#pragma unroll
    for (int i = 0; i < 4; ++i) {
      int tok = tok0 + lg * 4 + i;
      tidx[tok] = i1[i];
      oidx[tok] = (float)i1[i];
      if (m1[i] - m2v[i] < GAPTHR) {
        int p = atomicAdd(nfix, 1);
        fixlist[p] = tok;
      }
    }
  }
}

// ---- exact f64 rescore for close-call tokens (one wave per token) ----
__global__ __launch_bounds__(256) void k_fix(const float* __restrict__ x,
    const unsigned int* __restrict__ mask, const int* __restrict__ fixlist,
    const int* __restrict__ nfix, int* __restrict__ tidx, float* __restrict__ oidx)
{
  int n = *nfix;
  int l = threadIdx.x & 63;
  int gw = (blockIdx.x * 256 + threadIdx.x) >> 6;
  int nw = (gridDim.x * 256) >> 6;
  int t = l & 15, seg = l >> 4;

  for (int i = gw; i < n; i += nw) {
    int tok = fixlist[i];
    const float* xr = x + (size_t)tok * DM + seg * 256;
    const unsigned int* mr = mask + seg * 256;
    double acc0 = 0.0, acc1 = 0.0;
    for (int j = 0; j < 256; j += 4) {
      f32x4 xv = *(const f32x4*)(xr + j);
      u32x4 mv = *(const u32x4*)(mr + j);
#pragma unroll
      for (int u = 0; u < 4; ++u) {
        double c = ((mv[u] >> t) & 1u) ? (double)xv[u]
                 : (((mv[u] >> (16 + t)) & 1u) ? -(double)xv[u] : 0.0);
        if (u & 1) acc1 += c; else acc0 += c;
      }
    }
    double s = acc0 + acc1;
    s += __shfl_xor(s, 16);
    s += __shfl_xor(s, 32);
    double bv = s; int bi = t;
#pragma unroll
    for (int off = 1; off < 16; off <<= 1) {
      double ov = __shfl_xor(bv, off);
      int   oi = __shfl_xor(bi, off);
      if (ov > bv || (ov == bv && oi < bi)) { bv = ov; bi = oi; }
    }
    if (l == 0) { tidx[tok] = bi; oidx[tok] = (float)bi; }
  }
}

// ---- histogram of final routing ----
__global__ __launch_bounds__(256) void k_count(const int* __restrict__ tidx, int* __restrict__ counts) {
  __shared__ int h[16];
  if (threadIdx.x < 16) h[threadIdx.x] = 0;
  __syncthreads();
  int i = blockIdx.x * 256 + threadIdx.x;
  atomicAdd(&h[tidx[i]], 1);
  __syncthreads();
  if (threadIdx.x < 16 && h[threadIdx.x]) atomicAdd(&counts[threadIdx.x], h[threadIdx.x]);
}

// ---- W f32 -> bf16 ----
__global__ __launch_bounds__(256) void k_wconv(const float* __restrict__ W, unsigned short* __restrict__ Wb) {
  const f32x4* W4 = (const f32x4*)W;
  u16x4* O = (u16x4*)Wb;
  int n4 = NT * NC * DM / 4;
  for (int i = blockIdx.x * blockDim.x + threadIdx.x; i < n4; i += gridDim.x * blockDim.x) {
    f32x4 v = W4[i];
    u16x4 o;
#pragma unroll
    for (int j = 0; j < 4; ++j) o[j] = f2bf(v[j]);
    O[i] = o;
  }
}

// ---- padded exclusive scan of counts (pad to 256) ----
__global__ void k_scan(const int* __restrict__ counts, int* __restrict__ offs) {
  if (threadIdx.x == 0) {
    int s = 0;
    for (int t = 0; t < NT; ++t) {
      offs[t] = s;
      s += (counts[t] + 255) & ~255;
    }
    offs[NT] = s;
  }
}

// ---- scatter tokens into per-tile segments ----
__global__ __launch_bounds__(256) void k_place(const int* __restrict__ tidx, const int* __restrict__ offs,
                                               int* __restrict__ cursor, int* __restrict__ perm) {
  int tok = blockIdx.x * 256 + threadIdx.x;
  if (tok >= B_TOK) return;
  int t = tidx[tok];
  int pos = atomicAdd(&cursor[t], 1);
  perm[offs[t] + pos] = tok;
}

// ---- grouped GEMM: 256x256 tile, BK=32, 8 waves, ring-4 LDS, deep pipeline ----
// Ring of 4 K-tile slots (A 256x32 + B 256x32 each = 32KB; 128KB total). Prefetch 3 K-tiles
// ahead; counted vmcnt(8) once per K-tile (ledger: W_j drains kt j+1's 4 loads; tail 4/0).
// Swizzle: phys 8-elem granule = logical ^ ((row>>1)&3) (2 lanes/bank on ds_read_b128);
// staged via pre-swizzled per-lane GLOBAL source + linear LDS dest (rule 21).
__global__ __launch_bounds__(512, 2) void k_gemm(const unsigned short* __restrict__ xb,
    const unsigned short* __restrict__ Wb, const float* __restrict__ bias,
    const int* __restrict__ perm, const int* __restrict__ offs, float* __restrict__ out)
{
  __shared__ unsigned short lds[4][2][256 * 32];   // [slot][A/B][8192] = 128KB
  int bid0 = blockIdx.x;
  int bid = (bid0 & 7) * 136 + (bid0 >> 3);        // bijective XCD swizzle (1088 = 8*136)
  int mb = bid >> 2, nb = bid & 3;
  int total = offs[NT];
  int m0 = mb << 8;
  if (m0 >= total) return;
  int t = 0;
#pragma unroll
  for (int tt = 0; tt < NT; ++tt) if (m0 >= offs[tt + 1]) t = tt + 1;
  int c0 = nb << 8;
  int tid = threadIdx.x;

  // staging: round r covers rows r*128 + (tid>>2); phys 16B-slot = tid&3;
  // logical granule at that slot = (tid&3) ^ ((row>>1)&3) = (tid&3) ^ ((tid>>3)&3)
  int srow = tid >> 2;
  int kg = (((tid & 3) ^ ((tid >> 3) & 3)) << 3);  // element offset within 32-k row
  int tkA0 = perm[m0 + srow];        if (tkA0 < 0) tkA0 = 0;
  int tkA1 = perm[m0 + 128 + srow];  if (tkA1 < 0) tkA1 = 0;
  const unsigned short* pA0 = xb + (size_t)tkA0 * DM + kg;
  const unsigned short* pA1 = xb + (size_t)tkA1 * DM + kg;
  const unsigned short* gWt = Wb + (size_t)t * NC * DM;
  const unsigned short* pB0 = gWt + (size_t)(c0 + srow) * DM + kg;
  const unsigned short* pB1 = gWt + (size_t)(c0 + 128 + srow) * DM + kg;

  f32x4 acc[8][4];
#pragma unroll
  for (int m = 0; m < 8; ++m)
#pragma unroll
    for (int n = 0; n < 4; ++n) acc[m][n] = (f32x4){0.f, 0.f, 0.f, 0.f};

  int wid = tid >> 6, l = tid & 63;
  int wr = wid >> 2, wc = wid & 3;                 // 2M x 4N waves; per-wave out 128x64
  int lr = l & 15, lk = l >> 4;
  int wr128 = wr * 128, wc64 = wc * 64;
  int goff = ((lk ^ ((lr >> 1) & 3)) << 3);        // swizzled read granule offset

#define GLDS(g, lp) __builtin_amdgcn_global_load_lds(AS1(g), AS3(lp), 16, 0, 0)
#define STAGE_A(SS, KT) { \
  GLDS(pA0 + (KT) * 32, &lds[SS][0][tid * 8]); \
  GLDS(pA1 + (KT) * 32, &lds[SS][0][(512 + tid) * 8]); }
#define STAGE_B(SS, KT) { \
  GLDS(pB0 + (KT) * 32, &lds[SS][1][tid * 8]); \
  GLDS(pB1 + (KT) * 32, &lds[SS][1][(512 + tid) * 8]); }
#define RD_A(SLOT, M) (*(const short8*)&lds[SLOT][0][(wr128 + (M) * 16 + lr) * 32 + goff])
#define RD_B(SLOT, N) (*(const short8*)&lds[SLOT][1][(wc64 + (N) * 16 + lr) * 32 + goff])
#define MF(M_, N_, AV, BV) acc[M_][N_] = __builtin_amdgcn_mfma_f32_16x16x32_bf16(AV, BV, acc[M_][N_], 0, 0, 0)
#define MFMA16(MB, A0_, A1_, A2_, A3_) { \
  MF(MB + 0, 0, A0_, b0); MF(MB + 0, 1, A0_, b1); MF(MB + 0, 2, A0_, b2); MF(MB + 0, 3, A0_, b3); \
  MF(MB + 1, 0, A1_, b0); MF(MB + 1, 1, A1_, b1); MF(MB + 1, 2, A1_, b2); MF(MB + 1, 3, A1_, b3); \
  MF(MB + 2, 0, A2_, b0); MF(MB + 2, 1, A2_, b1); MF(MB + 2, 2, A2_, b2); MF(MB + 2, 3, A2_, b3); \
  MF(MB + 3, 0, A3_, b0); MF(MB + 3, 1, A3_, b1); MF(MB + 3, 2, A3_, b2); MF(MB + 3, 3, A3_, b3); }
#define VM8() asm volatile("s_waitcnt vmcnt(8)" ::: "memory")
#define VM4() asm volatile("s_waitcnt vmcnt(4)" ::: "memory")
#define VM0() asm volatile("s_waitcnt vmcnt(0)" ::: "memory")
#define PH_SYNC() { \
  __builtin_amdgcn_s_barrier(); \
  asm volatile("s_waitcnt lgkmcnt(0)" ::: "memory"); \
  __builtin_amdgcn_sched_barrier(0); }

#define KTILE(KT, SLOT, SS, DOSTAGE, VMW) { \
  short8 a0, a1, a2, a3, b0, b1, b2, b3; \
  a0 = RD_A(SLOT, 0); a1 = RD_A(SLOT, 1); a2 = RD_A(SLOT, 2); a3 = RD_A(SLOT, 3); \
  b0 = RD_B(SLOT, 0); b1 = RD_B(SLOT, 1); b2 = RD_B(SLOT, 2); b3 = RD_B(SLOT, 3); \
  if (DOSTAGE) STAGE_A(SS, (KT) + 3); \
  PH_SYNC(); \
  __builtin_amdgcn_s_setprio(1); \
  MFMA16(0, a0, a1, a2, a3); \
  __builtin_amdgcn_s_setprio(0); \
  __builtin_amdgcn_s_barrier(); \
  a0 = RD_A(SLOT, 4); a1 = RD_A(SLOT, 5); a2 = RD_A(SLOT, 6); a3 = RD_A(SLOT, 7); \
  if (DOSTAGE) STAGE_B(SS, (KT) + 3); \
  VMW; \
  PH_SYNC(); \
  __builtin_amdgcn_s_setprio(1); \
  MFMA16(4, a0, a1, a2, a3); \
  __builtin_amdgcn_s_setprio(0); \
  __builtin_amdgcn_s_barrier(); }

  // prologue: stage K-tiles 0,1,2 into slots 0,1,2; certify kt0
  STAGE_A(0, 0); STAGE_B(0, 0);
  STAGE_A(1, 1); STAGE_B(1, 1);
  STAGE_A(2, 2); STAGE_B(2, 2);
  VM8();
  __builtin_amdgcn_s_barrier();

#pragma unroll 1
  for (int kt = 0; kt < 28; kt += 4) {
    KTILE(kt + 0, 0, 3, 1, VM8());
    KTILE(kt + 1, 1, 0, 1, VM8());
    KTILE(kt + 2, 2, 1, 1, VM8());
    KTILE(kt + 3, 3, 2, 1, VM8());
  }
  KTILE(28, 0, 3, 1, VM8());
  KTILE(29, 1, 0, 0, VM4());
  KTILE(30, 2, 1, 0, VM0());
  KTILE(31, 3, 2, 0, ((void)0));

  // epilogue: C row(token) = m0 + wr*128 + m*16 + lk*4 + j; col(class) = c0 + wc*64 + n*16 + lr
  float bv[4];
#pragma unroll
  for (int n = 0; n < 4; ++n) bv[n] = bias[t * NC + c0 + wc64 + n * 16 + lr];
#pragma unroll
  for (int m = 0; m < 8; ++m) {
#pragma unroll
    for (int j = 0; j < 4; ++j) {
      int prow = m0 + wr128 + m * 16 + lk * 4 + j;
      int tok = perm[prow];
      if (tok >= 0) {
#pragma unroll
        for (int n = 0; n < 4; ++n)
          out[(size_t)tok * NC + c0 + wc64 + n * 16 + lr] = acc[m][n][j] + bv[n];
      }
    }
  }
}

extern "C" void kernel_launch(void* const* d_in, const int* in_sizes, int n_in,
                              void* d_out, int out_size, void* d_ws, size_t ws_size,
                              hipStream_t stream) {
  const float* x    = (const float*)d_in[0];
  const float* sigs = (const float*)d_in[1];
  const float* W    = (const float*)d_in[2];
  const float* bias = (const float*)d_in[3];
  float* out = (float*)d_out;
  float* oidx = out + (size_t)B_TOK * NC;

  char* ws = (char*)d_ws;
  unsigned short* xb   = (unsigned short*)ws;                    // 134217728 B
  unsigned short* Wb   = (unsigned short*)(ws + 134217728);      // 33554432 B
  int* perm            = (int*)(ws + 167772160);                 // 278528 B (69632 rows, 256-pad)
  int* tidx            = (int*)(ws + 168050688);                 // 262144 B
  unsigned int* mask   = (unsigned int*)(ws + 168312832);        // 4096 B
  unsigned short* Sb   = (unsigned short*)(ws + 168316928);      // 32768 B
  int* fixlist         = (int*)(ws + 168349696);                 // 262144 B
  int* ctrl            = (int*)(ws + 168611840);                 // counts16 cursor16 offs17 nfix1
  int* counts = ctrl;
  int* cursor = ctrl + 16;
  int* offs   = ctrl + 32;
  int* nfix   = ctrl + 49;

  hipMemsetAsync(perm, 0xFF, 278528, stream);   // perm = -1 (pad marker)
  hipMemsetAsync(ctrl, 0, 256, stream);

  k_prep<<<1, 1024, 0, stream>>>(sigs, mask, Sb);
  k_scores<<<1024, 256, 0, stream>>>(x, Sb, xb, tidx, oidx, fixlist, nfix);
  k_fix<<<512, 256, 0, stream>>>(x, mask, fixlist, nfix, tidx, oidx);
  k_count<<<256, 256, 0, stream>>>(tidx, counts);
  k_scan<<<1, 64, 0, stream>>>(counts, offs);
  k_place<<<256, 256, 0, stream>>>(tidx, offs, cursor, perm);
  k_wconv<<<2048, 256, 0, stream>>>(W, Wb);
  k_gemm<<<dim3(272 * 4), 512, 0, stream>>>(xb, Wb, bias, perm, offs, out);
}